// Round 1
// baseline (303.646 us; speedup 1.0000x reference)
//
#include <hip/hip_runtime.h>
#include <hip/hip_fp16.h>

#define BB 32
#define NI 2048
#define NK 64
#define ND 32
#define NL 16
#define KD (NK*ND)        // 2048
#define CHUNK 32
#define NCH (NI/CHUNK)    // 64
#define EPSF 1e-7f

struct __align__(16) H8 { __half2 h[4]; };
struct __align__(8)  H4 { __half2 h[2]; };

// K1: u_hat[b][i][k][d] (f16) = sum_l W[i][k][d][l] * x[b][i][l]
// grid = NI blocks, 512 threads; thread t owns cells 4t..4t+3 of the 2048 (k,d) cells.
__global__ __launch_bounds__(512) void k_uhat(const float* __restrict__ x,
                                              const float* __restrict__ W,
                                              __half* __restrict__ uhat) {
  const int i = blockIdx.x;
  const int t = threadIdx.x;
  __shared__ float xs[BB * NL];  // 512 floats
  {
    const int b = t >> 4, l = t & 15;
    xs[t] = x[((size_t)b * NI + i) * NL + l];
  }
  __syncthreads();
  float w[4][NL];
  const float* Wp = W + (size_t)i * KD * NL + (size_t)t * 4 * NL;
  #pragma unroll
  for (int c = 0; c < 4; ++c)
    #pragma unroll
    for (int q = 0; q < 4; ++q)
      *(float4*)&w[c][q * 4] = *(const float4*)(Wp + c * NL + q * 4);
  __half* up = uhat + (size_t)i * KD + (size_t)t * 4;
  for (int b = 0; b < BB; ++b) {
    float a0 = 0.f, a1 = 0.f, a2 = 0.f, a3 = 0.f;
    #pragma unroll
    for (int l = 0; l < NL; ++l) {
      const float xv = xs[b * NL + l];
      a0 += w[0][l] * xv; a1 += w[1][l] * xv;
      a2 += w[2][l] * xv; a3 += w[3][l] * xv;
    }
    H4 o;
    o.h[0] = __floats2half2_rn(a0, a1);
    o.h[1] = __floats2half2_rn(a2, a3);
    *(H4*)(up + (size_t)b * NI * KD) = o;
  }
}

// K2: round-0 partial sums: s0_partial[b][ch][cell] = (1/64) * sum_{i in chunk} u_hat
// grid = (NCH, BB), 256 threads; thread owns 8 cells (t*8..t*8+7).
__global__ __launch_bounds__(256) void k_round0(const __half* __restrict__ uhat,
                                                float* __restrict__ partial) {
  const int ch = blockIdx.x, b = blockIdx.y, t = threadIdx.x;
  float acc[8];
  #pragma unroll
  for (int j = 0; j < 8; ++j) acc[j] = 0.f;
  const __half* up = uhat + ((size_t)b * NI + (size_t)ch * CHUNK) * KD + t * 8;
  for (int il = 0; il < CHUNK; ++il) {
    H8 u = *(const H8*)(up + (size_t)il * KD);
    #pragma unroll
    for (int j = 0; j < 4; ++j) {
      float2 f = __half22float2(u.h[j]);
      acc[2 * j]     += f.x;
      acc[2 * j + 1] += f.y;
    }
  }
  float* pp = partial + ((size_t)b * NCH + ch) * KD + t * 8;
  #pragma unroll
  for (int j = 0; j < 8; ++j) pp[j] = acc[j] * (1.f / 64.f);
}

// K3/K5: routing pass. Per (b, chunk): for each i, agreement = sum_d u*v_prev,
// logits, softmax over k=64, s-accumulate. ROUND==1 stores b-logits; ROUND==2 reads them.
template <int ROUND>
__global__ __launch_bounds__(256) void k_route(const __half* __restrict__ uhat,
                                               const float* __restrict__ vin,
                                               const float* __restrict__ bin,
                                               float* __restrict__ bout,
                                               float* __restrict__ partial) {
  const int ch = blockIdx.x, b = blockIdx.y, t = threadIdx.x;
  const int k = t >> 2;          // 0..63 (4 threads per k, 8 d each)
  const int lane = t & 63, w = t >> 6;
  float vr[8];
  {
    const float* vp = vin + (size_t)b * KD + t * 8;
    #pragma unroll
    for (int j = 0; j < 8; ++j) vr[j] = vp[j];
  }
  float sacc[8];
  #pragma unroll
  for (int j = 0; j < 8; ++j) sacc[j] = 0.f;
  __shared__ float smax[4], ssum[4];
  const __half* up = uhat + ((size_t)b * NI + (size_t)ch * CHUNK) * KD + t * 8;
  const float* bip = bin + ((size_t)b * NI + (size_t)ch * CHUNK) * NK + k;
  float* bop = (ROUND == 1) ? bout + ((size_t)b * NI + (size_t)ch * CHUNK) * NK + k : nullptr;
  for (int il = 0; il < CHUNK; ++il) {
    H8 u = *(const H8*)(up + (size_t)il * KD);
    float uf[8];
    #pragma unroll
    for (int j = 0; j < 4; ++j) {
      float2 f = __half22float2(u.h[j]);
      uf[2 * j] = f.x; uf[2 * j + 1] = f.y;
    }
    float p = 0.f;
    #pragma unroll
    for (int j = 0; j < 8; ++j) p += uf[j] * vr[j];
    p += __shfl_xor(p, 1);
    p += __shfl_xor(p, 2);          // p = agreement[b, i, k] (all 4 lanes of group)
    float bn = p;
    if (ROUND == 2) bn += bip[il * NK];
    if (ROUND == 1) { if ((t & 3) == 0) bop[il * NK] = p; }
    // softmax over k=64: wave-reduce (16 k per wave) then cross-wave via LDS
    float m = bn;
    m = fmaxf(m, __shfl_xor(m, 4));
    m = fmaxf(m, __shfl_xor(m, 8));
    m = fmaxf(m, __shfl_xor(m, 16));
    m = fmaxf(m, __shfl_xor(m, 32));
    if (lane == 0) smax[w] = m;
    __syncthreads();
    m = fmaxf(fmaxf(smax[0], smax[1]), fmaxf(smax[2], smax[3]));
    const float e = __expf(bn - m);
    float s = e;
    s += __shfl_xor(s, 4);
    s += __shfl_xor(s, 8);
    s += __shfl_xor(s, 16);
    s += __shfl_xor(s, 32);
    if (lane == 0) ssum[w] = s;
    __syncthreads();
    s = ssum[0] + ssum[1] + ssum[2] + ssum[3];
    const float c = e / s;
    #pragma unroll
    for (int j = 0; j < 8; ++j) sacc[j] += c * uf[j];
  }
  float* pp = partial + ((size_t)b * NCH + ch) * KD + t * 8;
  #pragma unroll
  for (int j = 0; j < 8; ++j) pp[j] = sacc[j];
}

// K reduce: s[b][cell] = sum_ch partial, then squash over d -> vout[b][cell]
// grid = (8, BB), 256 threads; cell = g*256+t, d = cell&31 (32-lane aligned groups share k).
__global__ __launch_bounds__(256) void k_reduce(const float* __restrict__ partial,
                                                float* __restrict__ vout) {
  const int g = blockIdx.x, b = blockIdx.y, t = threadIdx.x;
  const int cell = g * 256 + t;
  float s = 0.f;
  const float* pp = partial + (size_t)b * NCH * KD + cell;
  for (int ch = 0; ch < NCH; ++ch) s += pp[(size_t)ch * KD];
  float sq = s * s;
  sq += __shfl_xor(sq, 1);
  sq += __shfl_xor(sq, 2);
  sq += __shfl_xor(sq, 4);
  sq += __shfl_xor(sq, 8);
  sq += __shfl_xor(sq, 16);
  sq += EPSF;
  const float scale = sqrtf(sq) / (1.f + sq);
  vout[(size_t)b * KD + cell] = s * scale;
}

extern "C" void kernel_launch(void* const* d_in, const int* in_sizes, int n_in,
                              void* d_out, int out_size, void* d_ws, size_t ws_size,
                              hipStream_t stream) {
  const float* x = (const float*)d_in[0];   // [32, 2048, 16]
  const float* W = (const float*)d_in[1];   // [2048, 64, 32, 16]
  float* out = (float*)d_out;               // [32, 64, 32]
  char* ws = (char*)d_ws;
  __half* uhat  = (__half*)ws;                                   // 268435456 B
  float* blog   = (float*)(ws + 268435456ull);                   // 16777216 B
  float* part   = (float*)(ws + 268435456ull + 16777216ull);     // 16777216 B
  float* v      = (float*)(ws + 268435456ull + 2ull * 16777216); // 262144 B

  k_uhat<<<NI, 512, 0, stream>>>(x, W, uhat);
  k_round0<<<dim3(NCH, BB), 256, 0, stream>>>(uhat, part);
  k_reduce<<<dim3(8, BB), 256, 0, stream>>>(part, v);            // v0
  k_route<1><<<dim3(NCH, BB), 256, 0, stream>>>(uhat, v, v, blog, part);
  k_reduce<<<dim3(8, BB), 256, 0, stream>>>(part, v);            // v1
  k_route<2><<<dim3(NCH, BB), 256, 0, stream>>>(uhat, v, blog, nullptr, part);
  k_reduce<<<dim3(8, BB), 256, 0, stream>>>(part, out);          // v2 -> out
}